// Round 5
// baseline (477.180 us; speedup 1.0000x reference)
//
#include <hip/hip_runtime.h>
#include <hip/hip_bf16.h>
#include <stdint.h>

#define NB 32
#define NS 4096
#define ND 512

typedef __attribute__((ext_vector_type(8))) short short8;
typedef __attribute__((ext_vector_type(4))) float floatx4;
typedef __attribute__((ext_vector_type(4))) unsigned int uint4v;

__device__ __forceinline__ short f2bf(float f) {
    unsigned int u = __builtin_bit_cast(unsigned int, f);
    return (short)((u + 0x8000u) >> 16);
}

// one instr, packs 2 f32 -> 2 bf16 (RNE)
__device__ __forceinline__ unsigned int cvt_pk_bf16(float lo, float hi) {
    unsigned int r;
    asm("v_cvt_pk_bf16_f32 %0, %1, %2" : "=v"(r) : "v"(lo), "v"(hi));
    return r;
}

__device__ __forceinline__ float fast_tanh(float x) {
    float e = __expf(2.0f * x);
    return 1.0f - 2.0f * __builtin_amdgcn_rcpf(e + 1.0f);
}

// K1a: qb[b][e] = sum_k query[b][k] * W1[k][e] + b1[e] + b2[e]
__global__ void __launch_bounds__(256) qproj_kernel(
    const float* __restrict__ query, const float* __restrict__ W1,
    const float* __restrict__ b1, const float* __restrict__ b2,
    float* __restrict__ qb) {
    const int b  = blockIdx.x;
    const int es = blockIdx.y;
    const int t  = threadIdx.x;
    const int col = t & 63, kc = t >> 6;
    __shared__ float q[ND];
    __shared__ float red[256];
    q[t] = query[b * ND + t];
    q[t + 256] = query[b * ND + t + 256];
    __syncthreads();
    float acc = 0.f;
    const float* wp = W1 + (size_t)(kc * 128) * ND + es * 64 + col;
    const float* qp = q + kc * 128;
#pragma unroll 8
    for (int k = 0; k < 128; k++)
        acc += qp[k] * wp[(size_t)k * ND];
    red[t] = acc;
    __syncthreads();
    if (t < 64) {
        float s = red[t] + red[t + 64] + red[t + 128] + red[t + 192];
        int e = es * 64 + t;
        qb[b * ND + e] = s + b1[e] + b2[e];
    }
}

// K1b: shuffle W2 (fp32 [k][e]) into bf16 tiled layout so each lane's MFMA
// B-fragment is one contiguous 16B chunk:
// chunk g = (nt: g>>14, ks: (g>>10)&15, kq: (g>>8)&3, n: g&255);
// holds bf16(W2[ks*32+kq*8+j][nt*256+n]) for j=0..7 at W2Tt + g*8.
__global__ void __launch_bounds__(256) w2t_kernel(
    const float* __restrict__ W2, unsigned short* __restrict__ W2Tt) {
    int g = blockIdx.x * 256 + threadIdx.x;   // 32768 chunks
    int nt = g >> 14;
    int ks = (g >> 10) & 15;
    int kq = (g >> 8) & 3;
    int n  = g & 255;
    int e  = nt * 256 + n;
    int k0 = ks * 32 + kq * 8;
    short8 v;
#pragma unroll
    for (int j = 0; j < 8; j++)
        v[j] = f2bf(W2[(size_t)(k0 + j) * ND + e]);
    *(short8*)&W2Tt[(size_t)g * 8] = v;
}

// K2: pscores[b][s] = sum_e tanh((values[b] @ W2)[s][e] + qb[b][e]) * V[e]
// BARRIER-FREE main loop. Per block: 64 s-rows, ALL 512 e-cols, K=512.
//   Phase 1 (once): stage values[b][s0..s0+64][0..512] as bf16 into sA[16][2048]
//     (one 4KB swizzled buffer per k-step; same zero-conflict layout as before),
//     fp32 HBM loads through a 4-deep register queue, ONE __syncthreads.
//   Phase 2: flattened loop hk=0..31 (e-half = hk>>4, k-step = hk&15):
//     4 ds_read_b128 (double-buffered, prefetch hk+1) + 4 L2 loads of W2Tt
//     (double-buffered; the ONLY outstanding vmem -> trivial vmcnt ordering)
//     + 16 MFMA. No s_barrier anywhere in the loop -> no convoy.
//   At each half boundary (ks==15): fold acc into p[i][r] via tanh*V, zero acc.
// values is read exactly ONCE device-wide; pscores is a single [32][4096] plane.
// LDS 69KB -> 2 blocks/CU; launch_bounds(256,2) caps VGPR at 256 (est ~190).
__global__ void __launch_bounds__(256, 2) scores_kernel(
    const float* __restrict__ values, const unsigned short* __restrict__ W2Tt,
    const float* __restrict__ qb, const float* __restrict__ V,
    float* __restrict__ pscores) {
    const int st = blockIdx.x;   // 0..63
    const int b  = blockIdx.y;   // 0..31
    const int s0 = st * 64;

    __shared__ __align__(16) unsigned short sA[16][2048];  // 64 KB: [ks][row*32 + swz-chunk]
    __shared__ float sQb[ND];
    __shared__ float sV[ND];
    __shared__ float sRed[4][64];

    const int tid  = threadIdx.x;
    const int lane = tid & 63;
    const int wave = tid >> 6;          // 0..3 -> e-col offset wave*64 within half
    const int mr = lane & 15;
    const int q  = lane >> 4;

    sQb[tid] = qb[b * ND + tid];
    sQb[tid + 256] = qb[b * ND + tid + 256];
    sV[tid]  = V[tid];
    sV[tid + 256] = V[tid + 256];

    // ---- phase 1: stage the whole 64x512 A-tile as bf16 into LDS ----
    // thread -> (row = tid>>2, k-chunk c = tid&3) of each 32-k step;
    // chunk stored at position c ^ ((row>>1)&3): zero-conflict (measured r1).
    const int arow = tid >> 2;
    const int ac   = tid & 3;
    const int ardo = arow * 32 + ((ac ^ ((tid >> 3) & 3)) * 8);  // short offset, 16B aligned
    const float* ag = values + ((size_t)b * NS + s0 + arow) * ND + ac * 8;

    {
        float4 aq[4][2];   // 4-deep HBM queue, compile-time slots
#pragma unroll
        for (int u = 0; u < 4; u++) {
            aq[u][0] = *(const float4*)(ag + u * 32);
            aq[u][1] = *(const float4*)(ag + u * 32 + 4);
        }
#pragma unroll
        for (int ks = 0; ks < 16; ks++) {
            const float4 a0 = aq[ks & 3][0], a1 = aq[ks & 3][1];
            if (ks < 12) {
                aq[ks & 3][0] = *(const float4*)(ag + (ks + 4) * 32);
                aq[ks & 3][1] = *(const float4*)(ag + (ks + 4) * 32 + 4);
            }
            uint4v w;
            w.x = cvt_pk_bf16(a0.x, a0.y); w.y = cvt_pk_bf16(a0.z, a0.w);
            w.z = cvt_pk_bf16(a1.x, a1.y); w.w = cvt_pk_bf16(a1.z, a1.w);
            *(uint4v*)&sA[ks][ardo] = w;
        }
    }
    __syncthreads();   // the ONLY block-wide barrier before the epilogue

    // ---- phase 2: barrier-free MFMA loop over hk = e-half*16 + k-step ----
    // frag-read chunk offset: row=i*16+mr -> (row>>1)&3 == (mr>>1)&3
    const int afo = (q ^ ((mr >> 1) & 3)) * 8;
    // per-lane B chunk base: (kq=q, n = wave*64 + j*16 + mr); hk adds 8192 shorts
    const unsigned short* bp = W2Tt + (q * 256 + wave * 64 + mr) * 8;

    floatx4 acc[4][4] = {};
    float p[4][4] = {};
    short8 af[2][4], bq[2][4];

#pragma unroll
    for (int i = 0; i < 4; i++)
        af[0][i] = *(const short8*)&sA[0][(i * 16 + mr) * 32 + afo];
#pragma unroll
    for (int j = 0; j < 4; j++)
        bq[0][j] = *(const short8*)(bp + j * 128);

#pragma unroll
    for (int hk = 0; hk < 32; hk++) {
        const int cur = hk & 1, nxt = cur ^ 1;
        const int ks = hk & 15;

        if (hk < 31) {
            // issue B(hk+1) from L2 (only vmem stream -> clean in-order retire)
            const unsigned short* bsrc = bp + (size_t)(hk + 1) * 8192;
#pragma unroll
            for (int j = 0; j < 4; j++)
                bq[nxt][j] = *(const short8*)(bsrc + j * 128);
            // prefetch A frags for (hk+1) from LDS
#pragma unroll
            for (int i = 0; i < 4; i++)
                af[nxt][i] = *(const short8*)&sA[(hk + 1) & 15][(i * 16 + mr) * 32 + afo];
        }

        __builtin_amdgcn_s_setprio(1);
#pragma unroll
        for (int i = 0; i < 4; i++)
#pragma unroll
            for (int j = 0; j < 4; j++)
                acc[i][j] = __builtin_amdgcn_mfma_f32_16x16x32_bf16(af[cur][i], bq[cur][j], acc[i][j], 0, 0, 0);
        __builtin_amdgcn_s_setprio(0);

        if (ks == 15) {
            // fold this e-half into p, reset acc (overlaps with sibling wave's MFMAs)
            const int h = hk >> 4;
            float vcoef[4], qadd[4];
#pragma unroll
            for (int j = 0; j < 4; j++) {
                int col = h * 256 + wave * 64 + j * 16 + mr;
                vcoef[j] = sV[col];
                qadd[j]  = sQb[col];
            }
#pragma unroll
            for (int i = 0; i < 4; i++)
#pragma unroll
                for (int r = 0; r < 4; r++) {
                    float s = 0.f;
#pragma unroll
                    for (int j = 0; j < 4; j++)
                        s += fast_tanh(acc[i][j][r] + qadd[j]) * vcoef[j];
                    p[i][r] += s;
                    if (hk < 31) acc[i][0][r] = 0.f;
                }
            if (hk < 31) {
#pragma unroll
                for (int i = 0; i < 4; i++)
#pragma unroll
                    for (int j = 1; j < 4; j++)
                        acc[i][j] = floatx4{0.f, 0.f, 0.f, 0.f};
            }
        }
    }

    // ---- final cross-lane / cross-wave reduce over e ----
#pragma unroll
    for (int i = 0; i < 4; i++) {
#pragma unroll
        for (int r = 0; r < 4; r++) {
            float v = p[i][r];
            v += __shfl_xor(v, 1);
            v += __shfl_xor(v, 2);
            v += __shfl_xor(v, 4);
            v += __shfl_xor(v, 8);
            if (mr == 0) sRed[wave][i * 16 + q * 4 + r] = v;
        }
    }
    __syncthreads();
    if (tid < 64) {
        float s = sRed[0][tid] + sRed[1][tid] + sRed[2][tid] + sRed[3][tid];
        pscores[(size_t)b * NS + s0 + tid] = s;
    }
}

// K3: softmax over S per batch (single score plane)
__global__ void __launch_bounds__(256) softmax_kernel(
    const float* __restrict__ pscores, float* __restrict__ attn) {
    int b = blockIdx.x;
    int t = threadIdx.x;
    __shared__ float red[4];
    __shared__ float bcast[2];
    const float* sc = pscores + (size_t)b * NS;
    float v[16];
    float m = -1e30f;
#pragma unroll
    for (int i = 0; i < 16; i++) { v[i] = sc[t + i * 256]; m = fmaxf(m, v[i]); }
    for (int o = 32; o; o >>= 1) m = fmaxf(m, __shfl_xor(m, o));
    if ((t & 63) == 0) red[t >> 6] = m;
    __syncthreads();
    if (t == 0) bcast[0] = fmaxf(fmaxf(red[0], red[1]), fmaxf(red[2], red[3]));
    __syncthreads();
    m = bcast[0];
    float sum = 0.f;
#pragma unroll
    for (int i = 0; i < 16; i++) { v[i] = __expf(v[i] - m); sum += v[i]; }
    for (int o = 32; o; o >>= 1) sum += __shfl_xor(sum, o);
    if ((t & 63) == 0) red[t >> 6] = sum;
    __syncthreads();
    if (t == 0) bcast[1] = red[0] + red[1] + red[2] + red[3];
    __syncthreads();
    float inv = 1.0f / bcast[1];
    float* ao = attn + (size_t)b * NS;
#pragma unroll
    for (int i = 0; i < 16; i++) ao[t + i * 256] = v[i] * inv;
}

// K4a: pctx[sc][b][d] = sum_{s in 128-chunk} attn[b][s] * values[b][s][d]
// 1024 blocks (4/CU); each thread owns a d-pair (8B float2), 128 MACs/thread.
__global__ void __launch_bounds__(256) context_partial_kernel(
    const float* __restrict__ values, const float* __restrict__ attn,
    float* __restrict__ pctx) {
    int sc = blockIdx.x;  // 0..31 (128 s each)
    int b  = blockIdx.y;  // 0..31
    int t  = threadIdx.x;
    __shared__ float sAttn[128];
    if (t < 128) sAttn[t] = attn[(size_t)b * NS + sc * 128 + t];
    __syncthreads();
    int d = t * 2;
    const float2* vp = (const float2*)(values + ((size_t)b * NS + sc * 128) * ND + d);
    float ax = 0.f, ay = 0.f;
#pragma unroll 8
    for (int s = 0; s < 128; s++) {
        float a = sAttn[s];
        float2 v = vp[(size_t)s * 256];
        ax += a * v.x; ay += a * v.y;
    }
    pctx[((size_t)sc * 32 + b) * ND + d]     = ax;
    pctx[((size_t)sc * 32 + b) * ND + d + 1] = ay;
}

// K4b: ctx[b][d] = sum_sc pctx[sc][b][d]
__global__ void __launch_bounds__(256) context_reduce_kernel(
    const float* __restrict__ pctx, float* __restrict__ ctx) {
    int i = blockIdx.x * 256 + threadIdx.x;  // 16384
    float s = 0.f;
#pragma unroll
    for (int p = 0; p < 32; p++) s += pctx[(size_t)p * (32 * ND) + i];
    ctx[i] = s;
}

extern "C" void kernel_launch(void* const* d_in, const int* in_sizes, int n_in,
                              void* d_out, int out_size, void* d_ws, size_t ws_size,
                              hipStream_t stream) {
    const float* query  = (const float*)d_in[0];
    const float* values = (const float*)d_in[1];
    const float* W1     = (const float*)d_in[2];
    const float* b1     = (const float*)d_in[3];
    const float* W2     = (const float*)d_in[4];
    const float* b2     = (const float*)d_in[5];
    const float* V      = (const float*)d_in[6];
    // d_in[7] = bv: uniform shift over softmax axis -> no effect on outputs. Dropped.

    float* ctx_out  = (float*)d_out;               // [32,512]
    float* attn_out = (float*)d_out + NB * ND;     // [32,4096]

    char* ws = (char*)d_ws;
    float*          qb      = (float*)ws;                              // 64 KB
    unsigned short* W2Tt    = (unsigned short*)(ws + (64 << 10));      // 512 KB
    float*          pscores = (float*)(ws + (576 << 10));              // 512 KB: [32][4096]
    float*          pctx    = (float*)(ws + (1088 << 10));             // 2 MB: [32][32][512]

    qproj_kernel<<<dim3(NB, 8), 256, 0, stream>>>(query, W1, b1, b2, qb);
    w2t_kernel<<<128, 256, 0, stream>>>(W2, W2Tt);
    scores_kernel<<<dim3(64, 32), 256, 0, stream>>>(values, W2Tt, qb, V, pscores);
    softmax_kernel<<<NB, 256, 0, stream>>>(pscores, attn_out);
    context_partial_kernel<<<dim3(32, 32), 256, 0, stream>>>(values, attn_out, pctx);
    context_reduce_kernel<<<64, 256, 0, stream>>>(pctx, ctx_out);
}

// Round 7
// 459.856 us; speedup vs baseline: 1.0377x; 1.0377x over previous
//
#include <hip/hip_runtime.h>
#include <hip/hip_bf16.h>
#include <stdint.h>

#define NB 32
#define NS 4096
#define ND 512

typedef __attribute__((ext_vector_type(8))) short short8;
typedef __attribute__((ext_vector_type(4))) float floatx4;
typedef __attribute__((ext_vector_type(2))) float floatx2;
typedef __attribute__((ext_vector_type(4))) unsigned int uint4v;

__device__ __forceinline__ short f2bf(float f) {
    unsigned int u = __builtin_bit_cast(unsigned int, f);
    return (short)((u + 0x8000u) >> 16);
}

// one instr, packs 2 f32 -> 2 bf16 (RNE)
__device__ __forceinline__ unsigned int cvt_pk_bf16(float lo, float hi) {
    unsigned int r;
    asm("v_cvt_pk_bf16_f32 %0, %1, %2" : "=v"(r) : "v"(lo), "v"(hi));
    return r;
}

__device__ __forceinline__ float fast_tanh(float x) {
    float e = __expf(2.0f * x);
    return 1.0f - 2.0f * __builtin_amdgcn_rcpf(e + 1.0f);
}

// K1: fused prep.
//  blocks 0..255:   qb[b][e] = sum_k query[b][k]*W1[k][e] + b1[e] + b2[e]
//  blocks 256..383: W2 (fp32 [k][e]) -> bf16 tiled W2Tt (16B chunk per lane-frag):
//    chunk g = (nt: g>>14, ks: (g>>10)&15, kq: (g>>8)&3, n: g&255);
//    holds bf16(W2[ks*32+kq*8+j][nt*256+n]), j=0..7, at W2Tt+g*8.
__global__ void __launch_bounds__(256) prep_kernel(
    const float* __restrict__ query, const float* __restrict__ W1,
    const float* __restrict__ b1, const float* __restrict__ b2,
    const float* __restrict__ W2,
    float* __restrict__ qb, unsigned short* __restrict__ W2Tt) {
    const int bx = blockIdx.x;
    const int t  = threadIdx.x;
    if (bx < 256) {
        const int b  = bx >> 3;
        const int es = bx & 7;
        const int col = t & 63, kc = t >> 6;
        __shared__ float q[ND];
        __shared__ float red[256];
        q[t] = query[b * ND + t];
        q[t + 256] = query[b * ND + t + 256];
        __syncthreads();
        float acc = 0.f;
        const float* wp = W1 + (size_t)(kc * 128) * ND + es * 64 + col;
        const float* qp = q + kc * 128;
#pragma unroll 8
        for (int k = 0; k < 128; k++)
            acc += qp[k] * wp[(size_t)k * ND];
        red[t] = acc;
        __syncthreads();
        if (t < 64) {
            float s = red[t] + red[t + 64] + red[t + 128] + red[t + 192];
            int e = es * 64 + t;
            qb[b * ND + e] = s + b1[e] + b2[e];
        }
    } else {
        int g = (bx - 256) * 256 + t;   // 32768 chunks
        int nt = g >> 14;
        int ks = (g >> 10) & 15;
        int kq = (g >> 8) & 3;
        int n  = g & 255;
        int e  = nt * 256 + n;
        int k0 = ks * 32 + kq * 8;
        short8 v;
#pragma unroll
        for (int j = 0; j < 8; j++)
            v[j] = f2bf(W2[(size_t)(k0 + j) * ND + e]);
        *(short8*)&W2Tt[(size_t)g * 8] = v;
    }
}

// K2: pscores[b][s] = sum_e tanh((values[b] @ W2)[s][e] + qb[b][e]) * V[e]
// Barrier-free main loop (r5 structure) + two fixes for the B-stall theory:
//  * values staged with NONTEMPORAL loads -> stops evicting W2Tt from L2
//    (values has zero reuse; W2Tt is the only data wanting residency).
//  * B prefetch deepened to 3 slots (issue hk+2 at hk): ~2 iterations (~1.2k cy)
//    of cover, enough for L3-latency hits even when L2 is polluted.
// Phase 1: stage values[b][s0..s0+64][:] as bf16 into sA[16][2048] (swizzled,
//   zero-conflict), fp32 through a 4-deep reg queue, ONE __syncthreads.
// Phase 2: hk=0..31 (e-half = hk>>4, k-step = hk&15): 4 ds_read_b128 (dbuf)
//   + 4 B loads (3-slot queue, only vmem stream -> clean in-order vmcnt)
//   + 16 MFMA. tanh-fold into p[] at each half boundary.
__global__ void __launch_bounds__(256, 2) scores_kernel(
    const float* __restrict__ values, const unsigned short* __restrict__ W2Tt,
    const float* __restrict__ qb, const float* __restrict__ V,
    float* __restrict__ pscores) {
    const int st = blockIdx.x;   // 0..63
    const int b  = blockIdx.y;   // 0..31
    const int s0 = st * 64;

    __shared__ __align__(16) unsigned short sA[16][2048];  // 64 KB
    __shared__ float sQb[ND];
    __shared__ float sV[ND];
    __shared__ float sRed[4][64];

    const int tid  = threadIdx.x;
    const int lane = tid & 63;
    const int wave = tid >> 6;
    const int mr = lane & 15;
    const int q  = lane >> 4;

    sQb[tid] = qb[b * ND + tid];
    sQb[tid + 256] = qb[b * ND + tid + 256];
    sV[tid]  = V[tid];
    sV[tid + 256] = V[tid + 256];

    // ---- phase 1: stage 64x512 A-tile as bf16 (nontemporal fp32 reads) ----
    const int arow = tid >> 2;
    const int ac   = tid & 3;
    const int ardo = arow * 32 + ((ac ^ ((tid >> 3) & 3)) * 8);
    const float* ag = values + ((size_t)b * NS + s0 + arow) * ND + ac * 8;

    {
        floatx4 aq[4][2];
#pragma unroll
        for (int u = 0; u < 4; u++) {
            aq[u][0] = __builtin_nontemporal_load((const floatx4*)(ag + u * 32));
            aq[u][1] = __builtin_nontemporal_load((const floatx4*)(ag + u * 32 + 4));
        }
#pragma unroll
        for (int ks = 0; ks < 16; ks++) {
            const floatx4 a0 = aq[ks & 3][0], a1 = aq[ks & 3][1];
            if (ks < 12) {
                aq[ks & 3][0] = __builtin_nontemporal_load((const floatx4*)(ag + (ks + 4) * 32));
                aq[ks & 3][1] = __builtin_nontemporal_load((const floatx4*)(ag + (ks + 4) * 32 + 4));
            }
            uint4v w;
            w.x = cvt_pk_bf16(a0.x, a0.y); w.y = cvt_pk_bf16(a0.z, a0.w);
            w.z = cvt_pk_bf16(a1.x, a1.y); w.w = cvt_pk_bf16(a1.z, a1.w);
            *(uint4v*)&sA[ks][ardo] = w;
        }
    }
    __syncthreads();   // only block-wide barrier before epilogue

    // ---- phase 2: barrier-free MFMA loop ----
    const int afo = (q ^ ((mr >> 1) & 3)) * 8;
    const unsigned short* bp = W2Tt + (q * 256 + wave * 64 + mr) * 8;

    floatx4 acc[4][4] = {};
    float p[4][4] = {};
    short8 af[2][4], bq[3][4];

#pragma unroll
    for (int i = 0; i < 4; i++)
        af[0][i] = *(const short8*)&sA[0][(i * 16 + mr) * 32 + afo];
#pragma unroll
    for (int j = 0; j < 4; j++)
        bq[0][j] = *(const short8*)(bp + j * 128);
#pragma unroll
    for (int j = 0; j < 4; j++)
        bq[1][j] = *(const short8*)(bp + 8192 + j * 128);

#pragma unroll
    for (int hk = 0; hk < 32; hk++) {
        const int cur = hk & 1, nxt = cur ^ 1;
        const int ks = hk & 15;

        // issue B(hk+2) into freed slot (2-iteration latency cover)
        if (hk < 30) {
            const unsigned short* bsrc = bp + (size_t)(hk + 2) * 8192;
#pragma unroll
            for (int j = 0; j < 4; j++)
                bq[(hk + 2) % 3][j] = *(const short8*)(bsrc + j * 128);
        }
        // prefetch A frags for hk+1 from LDS
        if (hk < 31) {
#pragma unroll
            for (int i = 0; i < 4; i++)
                af[nxt][i] = *(const short8*)&sA[(hk + 1) & 15][(i * 16 + mr) * 32 + afo];
        }

        __builtin_amdgcn_s_setprio(1);
#pragma unroll
        for (int i = 0; i < 4; i++)
#pragma unroll
            for (int j = 0; j < 4; j++)
                acc[i][j] = __builtin_amdgcn_mfma_f32_16x16x32_bf16(af[cur][i], bq[hk % 3][j], acc[i][j], 0, 0, 0);
        __builtin_amdgcn_s_setprio(0);

        if (ks == 15) {
            const int h = hk >> 4;
            float vcoef[4], qadd[4];
#pragma unroll
            for (int j = 0; j < 4; j++) {
                int col = h * 256 + wave * 64 + j * 16 + mr;
                vcoef[j] = sV[col];
                qadd[j]  = sQb[col];
            }
#pragma unroll
            for (int i = 0; i < 4; i++)
#pragma unroll
                for (int r = 0; r < 4; r++) {
                    float s = 0.f;
#pragma unroll
                    for (int j = 0; j < 4; j++)
                        s += fast_tanh(acc[i][j][r] + qadd[j]) * vcoef[j];
                    p[i][r] += s;
                    if (hk < 31) acc[i][0][r] = 0.f;
                }
            if (hk < 31) {
#pragma unroll
                for (int i = 0; i < 4; i++)
#pragma unroll
                    for (int j = 1; j < 4; j++)
                        acc[i][j] = floatx4{0.f, 0.f, 0.f, 0.f};
            }
        }
    }

    // ---- final cross-lane / cross-wave reduce over e ----
#pragma unroll
    for (int i = 0; i < 4; i++) {
#pragma unroll
        for (int r = 0; r < 4; r++) {
            float v = p[i][r];
            v += __shfl_xor(v, 1);
            v += __shfl_xor(v, 2);
            v += __shfl_xor(v, 4);
            v += __shfl_xor(v, 8);
            if (mr == 0) sRed[wave][i * 16 + q * 4 + r] = v;
        }
    }
    __syncthreads();
    if (tid < 64) {
        float s = sRed[0][tid] + sRed[1][tid] + sRed[2][tid] + sRed[3][tid];
        pscores[(size_t)b * NS + s0 + tid] = s;
    }
}

// K3: fused softmax + context partial.
// Each block (sc,b): (1) reads the full 4096 pscores row, derives row max & sum
// (deterministic, identical across blocks of the same b); (2) normalizes its own
// 128-row slice, writes attn[b][sc*128..]; (3) context MAC over its slice with
// nontemporal values reads. One launch instead of two; pscores row is L2-hot.
__global__ void __launch_bounds__(256) context_softmax_kernel(
    const float* __restrict__ values, const float* __restrict__ pscores,
    float* __restrict__ attn, float* __restrict__ pctx) {
    int sc = blockIdx.x;  // 0..31 (128 s each)
    int b  = blockIdx.y;  // 0..31
    int t  = threadIdx.x;
    __shared__ float sAttn[128];
    __shared__ float red[4];
    __shared__ float bcast[2];
    const float* srow = pscores + (size_t)b * NS;
    float v[16];
    float m = -1e30f;
#pragma unroll
    for (int i = 0; i < 16; i++) { v[i] = srow[t + i * 256]; m = fmaxf(m, v[i]); }
    for (int o = 32; o; o >>= 1) m = fmaxf(m, __shfl_xor(m, o));
    if ((t & 63) == 0) red[t >> 6] = m;
    __syncthreads();
    if (t == 0) bcast[0] = fmaxf(fmaxf(red[0], red[1]), fmaxf(red[2], red[3]));
    __syncthreads();
    m = bcast[0];
    float sum = 0.f;
#pragma unroll
    for (int i = 0; i < 16; i++) sum += __expf(v[i] - m);
    for (int o = 32; o; o >>= 1) sum += __shfl_xor(sum, o);
    if ((t & 63) == 0) red[t >> 6] = sum;
    __syncthreads();
    if (t == 0) bcast[1] = red[0] + red[1] + red[2] + red[3];
    __syncthreads();
    float inv = 1.0f / bcast[1];
    if (t < 128) {
        float w = __expf(srow[sc * 128 + t] - m) * inv;
        attn[(size_t)b * NS + sc * 128 + t] = w;
        sAttn[t] = w;
    }
    __syncthreads();
    int d = t * 2;
    const float* vp = values + ((size_t)b * NS + sc * 128) * ND + d;
    float ax = 0.f, ay = 0.f;
#pragma unroll 8
    for (int s = 0; s < 128; s++) {
        float a = sAttn[s];
        floatx2 vv = __builtin_nontemporal_load((const floatx2*)(vp + (size_t)s * ND));
        ax += a * vv.x; ay += a * vv.y;
    }
    pctx[((size_t)sc * 32 + b) * ND + d]     = ax;
    pctx[((size_t)sc * 32 + b) * ND + d + 1] = ay;
}

// K4: ctx[b][d] = sum_sc pctx[sc][b][d]
__global__ void __launch_bounds__(256) context_reduce_kernel(
    const float* __restrict__ pctx, float* __restrict__ ctx) {
    int i = blockIdx.x * 256 + threadIdx.x;  // 16384
    float s = 0.f;
#pragma unroll
    for (int p = 0; p < 32; p++) s += pctx[(size_t)p * (32 * ND) + i];
    ctx[i] = s;
}

extern "C" void kernel_launch(void* const* d_in, const int* in_sizes, int n_in,
                              void* d_out, int out_size, void* d_ws, size_t ws_size,
                              hipStream_t stream) {
    const float* query  = (const float*)d_in[0];
    const float* values = (const float*)d_in[1];
    const float* W1     = (const float*)d_in[2];
    const float* b1     = (const float*)d_in[3];
    const float* W2     = (const float*)d_in[4];
    const float* b2     = (const float*)d_in[5];
    const float* V      = (const float*)d_in[6];
    // d_in[7] = bv: uniform shift over softmax axis -> no effect on outputs. Dropped.

    float* ctx_out  = (float*)d_out;               // [32,512]
    float* attn_out = (float*)d_out + NB * ND;     // [32,4096]

    char* ws = (char*)d_ws;
    float*          qb      = (float*)ws;                              // 64 KB
    unsigned short* W2Tt    = (unsigned short*)(ws + (64 << 10));      // 512 KB
    float*          pscores = (float*)(ws + (576 << 10));              // 512 KB: [32][4096]
    float*          pctx    = (float*)(ws + (1088 << 10));             // 2 MB: [32][32][512]

    prep_kernel<<<384, 256, 0, stream>>>(query, W1, b1, b2, W2, qb, W2Tt);
    scores_kernel<<<dim3(64, 32), 256, 0, stream>>>(values, W2Tt, qb, V, pscores);
    context_softmax_kernel<<<dim3(32, 32), 256, 0, stream>>>(values, pscores, attn_out, pctx);
    context_reduce_kernel<<<64, 256, 0, stream>>>(pctx, ctx_out);
}

// Round 8
// 429.341 us; speedup vs baseline: 1.1114x; 1.0711x over previous
//
#include <hip/hip_runtime.h>
#include <hip/hip_bf16.h>
#include <stdint.h>

#define NB 32
#define NS 4096
#define ND 512

typedef __attribute__((ext_vector_type(8))) short short8;
typedef __attribute__((ext_vector_type(4))) float floatx4;
typedef __attribute__((ext_vector_type(2))) float floatx2;
typedef __attribute__((ext_vector_type(4))) unsigned int uint4v;

__device__ __forceinline__ short f2bf(float f) {
    unsigned int u = __builtin_bit_cast(unsigned int, f);
    return (short)((u + 0x8000u) >> 16);
}

// one instr, packs 2 f32 -> 2 bf16 (RNE)
__device__ __forceinline__ unsigned int cvt_pk_bf16(float lo, float hi) {
    unsigned int r;
    asm("v_cvt_pk_bf16_f32 %0, %1, %2" : "=v"(r) : "v"(lo), "v"(hi));
    return r;
}

__device__ __forceinline__ float fast_tanh(float x) {
    float e = __expf(2.0f * x);
    return 1.0f - 2.0f * __builtin_amdgcn_rcpf(e + 1.0f);
}

// K1: fused prep.
//  blocks 0..255:   qb[b][e] = sum_k query[b][k]*W1[k][e] + b1[e] + b2[e]
//  blocks 256..383: W2 (fp32 [k][e]) -> bf16 tiled W2Tt (16B chunk per lane-frag):
//    chunk g = (nt: g>>14, ks: (g>>10)&15, kq: (g>>8)&3, n: g&255);
//    holds bf16(W2[ks*32+kq*8+j][nt*256+n]), j=0..7, at W2Tt+g*8.
__global__ void __launch_bounds__(256) prep_kernel(
    const float* __restrict__ query, const float* __restrict__ W1,
    const float* __restrict__ b1, const float* __restrict__ b2,
    const float* __restrict__ W2,
    float* __restrict__ qb, unsigned short* __restrict__ W2Tt) {
    const int bx = blockIdx.x;
    const int t  = threadIdx.x;
    if (bx < 256) {
        const int b  = bx >> 3;
        const int es = bx & 7;
        const int col = t & 63, kc = t >> 6;
        __shared__ float q[ND];
        __shared__ float red[256];
        q[t] = query[b * ND + t];
        q[t + 256] = query[b * ND + t + 256];
        __syncthreads();
        float acc = 0.f;
        const float* wp = W1 + (size_t)(kc * 128) * ND + es * 64 + col;
        const float* qp = q + kc * 128;
#pragma unroll 8
        for (int k = 0; k < 128; k++)
            acc += qp[k] * wp[(size_t)k * ND];
        red[t] = acc;
        __syncthreads();
        if (t < 64) {
            float s = red[t] + red[t + 64] + red[t + 128] + red[t + 192];
            int e = es * 64 + t;
            qb[b * ND + e] = s + b1[e] + b2[e];
        }
    } else {
        int g = (bx - 256) * 256 + t;   // 32768 chunks
        int nt = g >> 14;
        int ks = (g >> 10) & 15;
        int kq = (g >> 8) & 3;
        int n  = g & 255;
        int e  = nt * 256 + n;
        int k0 = ks * 32 + kq * 8;
        short8 v;
#pragma unroll
        for (int j = 0; j < 8; j++)
            v[j] = f2bf(W2[(size_t)(k0 + j) * ND + e]);
        *(short8*)&W2Tt[(size_t)g * 8] = v;
    }
}

// K2: FUSED scores + local softmax + partial context (flash-style).
// Per (st,b) block over 64 s-rows:
//  phase 1: stage values[b][s0..s0+64][:] bf16 into sA[16][2048] (swizzled,
//    nontemporal fp32 reads, 4-deep reg queue, one __syncthreads) -- values is
//    read exactly ONCE device-wide by the whole pipeline now.
//  phase 2: barrier-free MFMA loop (r5/r7 structure): hk=0..31, 4 ds_read_b128
//    + 4 B loads (3-slot reg queue from W2Tt, only vmem stream) + 16 MFMA;
//    tanh(P+qb)*V fold into p[] at each e-half boundary.
//  phase 3: scores s[64] via shfl+LDS reduce -> local m = max, w = exp(s-m),
//    l = sum w; write (m,l) and pscores; then partial ctx from the LDS bf16
//    tile: pctx[st][b][d] = sum_row w[row]*values[row][d]. Combine kernel
//    merges chunks with exact softmax rescaling.
__global__ void __launch_bounds__(256, 2) scores_ctx_kernel(
    const float* __restrict__ values, const unsigned short* __restrict__ W2Tt,
    const float* __restrict__ qb, const float* __restrict__ V,
    float* __restrict__ pscores, float* __restrict__ pctx, float* __restrict__ ml) {
    const int st = blockIdx.x;   // 0..63
    const int b  = blockIdx.y;   // 0..31
    const int s0 = st * 64;

    __shared__ __align__(16) unsigned short sA[16][2048];  // 64 KB
    __shared__ float sQb[ND];
    __shared__ float sV[ND];
    __shared__ float sRed[4][64];
    __shared__ float sW[64];

    const int tid  = threadIdx.x;
    const int lane = tid & 63;
    const int wave = tid >> 6;
    const int mr = lane & 15;
    const int q  = lane >> 4;

    sQb[tid] = qb[b * ND + tid];
    sQb[tid + 256] = qb[b * ND + tid + 256];
    sV[tid]  = V[tid];
    sV[tid + 256] = V[tid + 256];

    // ---- phase 1: stage 64x512 A-tile as bf16 (nontemporal fp32 reads) ----
    const int arow = tid >> 2;
    const int ac   = tid & 3;
    const int ardo = arow * 32 + ((ac ^ ((tid >> 3) & 3)) * 8);
    const float* ag = values + ((size_t)b * NS + s0 + arow) * ND + ac * 8;

    {
        floatx4 aq[4][2];
#pragma unroll
        for (int u = 0; u < 4; u++) {
            aq[u][0] = __builtin_nontemporal_load((const floatx4*)(ag + u * 32));
            aq[u][1] = __builtin_nontemporal_load((const floatx4*)(ag + u * 32 + 4));
        }
#pragma unroll
        for (int ks = 0; ks < 16; ks++) {
            const floatx4 a0 = aq[ks & 3][0], a1 = aq[ks & 3][1];
            if (ks < 12) {
                aq[ks & 3][0] = __builtin_nontemporal_load((const floatx4*)(ag + (ks + 4) * 32));
                aq[ks & 3][1] = __builtin_nontemporal_load((const floatx4*)(ag + (ks + 4) * 32 + 4));
            }
            uint4v w;
            w.x = cvt_pk_bf16(a0.x, a0.y); w.y = cvt_pk_bf16(a0.z, a0.w);
            w.z = cvt_pk_bf16(a1.x, a1.y); w.w = cvt_pk_bf16(a1.z, a1.w);
            *(uint4v*)&sA[ks][ardo] = w;
        }
    }
    __syncthreads();

    // ---- phase 2: barrier-free MFMA loop ----
    const int afo = (q ^ ((mr >> 1) & 3)) * 8;
    const unsigned short* bp = W2Tt + (q * 256 + wave * 64 + mr) * 8;

    floatx4 acc[4][4] = {};
    float p[4][4] = {};
    short8 af[2][4], bq[3][4];

#pragma unroll
    for (int i = 0; i < 4; i++)
        af[0][i] = *(const short8*)&sA[0][(i * 16 + mr) * 32 + afo];
#pragma unroll
    for (int j = 0; j < 4; j++)
        bq[0][j] = *(const short8*)(bp + j * 128);
#pragma unroll
    for (int j = 0; j < 4; j++)
        bq[1][j] = *(const short8*)(bp + 8192 + j * 128);

#pragma unroll
    for (int hk = 0; hk < 32; hk++) {
        const int cur = hk & 1, nxt = cur ^ 1;
        const int ks = hk & 15;

        if (hk < 30) {
            const unsigned short* bsrc = bp + (size_t)(hk + 2) * 8192;
#pragma unroll
            for (int j = 0; j < 4; j++)
                bq[(hk + 2) % 3][j] = *(const short8*)(bsrc + j * 128);
        }
        if (hk < 31) {
#pragma unroll
            for (int i = 0; i < 4; i++)
                af[nxt][i] = *(const short8*)&sA[(hk + 1) & 15][(i * 16 + mr) * 32 + afo];
        }

        __builtin_amdgcn_s_setprio(1);
#pragma unroll
        for (int i = 0; i < 4; i++)
#pragma unroll
            for (int j = 0; j < 4; j++)
                acc[i][j] = __builtin_amdgcn_mfma_f32_16x16x32_bf16(af[cur][i], bq[hk % 3][j], acc[i][j], 0, 0, 0);
        __builtin_amdgcn_s_setprio(0);

        if (ks == 15) {
            const int h = hk >> 4;
            float vcoef[4], qadd[4];
#pragma unroll
            for (int j = 0; j < 4; j++) {
                int col = h * 256 + wave * 64 + j * 16 + mr;
                vcoef[j] = sV[col];
                qadd[j]  = sQb[col];
            }
#pragma unroll
            for (int i = 0; i < 4; i++)
#pragma unroll
                for (int r = 0; r < 4; r++) {
                    float s = 0.f;
#pragma unroll
                    for (int j = 0; j < 4; j++)
                        s += fast_tanh(acc[i][j][r] + qadd[j]) * vcoef[j];
                    p[i][r] += s;
                    if (hk < 31) acc[i][0][r] = 0.f;
                }
            if (hk < 31) {
#pragma unroll
                for (int i = 0; i < 4; i++)
#pragma unroll
                    for (int j = 1; j < 4; j++)
                        acc[i][j] = floatx4{0.f, 0.f, 0.f, 0.f};
            }
        }
    }

    // ---- phase 3a: scores reduce ----
#pragma unroll
    for (int i = 0; i < 4; i++) {
#pragma unroll
        for (int r = 0; r < 4; r++) {
            float v = p[i][r];
            v += __shfl_xor(v, 1);
            v += __shfl_xor(v, 2);
            v += __shfl_xor(v, 4);
            v += __shfl_xor(v, 8);
            if (mr == 0) sRed[wave][i * 16 + q * 4 + r] = v;
        }
    }
    __syncthreads();
    // ---- phase 3b: local softmax stats (wave 0: lane == row) ----
    if (tid < 64) {
        float sv = sRed[0][tid] + sRed[1][tid] + sRed[2][tid] + sRed[3][tid];
        pscores[(size_t)b * NS + s0 + tid] = sv;
        float m = sv;
        for (int o = 32; o; o >>= 1) m = fmaxf(m, __shfl_xor(m, o));
        float w = __expf(sv - m);
        float l = w;
        for (int o = 32; o; o >>= 1) l += __shfl_xor(l, o);
        sW[tid] = w;
        if (tid == 0) {
            int c = b * 64 + st;
            ml[c * 2]     = m;
            ml[c * 2 + 1] = l;
        }
    }
    __syncthreads();
    // ---- phase 3c: partial ctx from the LDS bf16 tile ----
    // thread owns d-pair (d0 = 2*tid): sA[d0>>5][row*32 + perm(row)*8 + (d0&7)]
    {
        const int d0  = tid * 2;
        const int ks2 = d0 >> 5;
        const int c2  = (d0 >> 3) & 3;
        const int j0  = d0 & 7;
        float cx = 0.f, cy = 0.f;
#pragma unroll 8
        for (int row = 0; row < 64; row++) {
            unsigned int u = *(const unsigned int*)
                &sA[ks2][row * 32 + ((c2 ^ ((row >> 1) & 3)) * 8) + j0];
            float w  = sW[row];
            float vx = __builtin_bit_cast(float, u << 16);
            float vy = __builtin_bit_cast(float, u & 0xffff0000u);
            cx += w * vx;
            cy += w * vy;
        }
        floatx2 o; o.x = cx; o.y = cy;
        *(floatx2*)&pctx[((size_t)st * NB + b) * ND + d0] = o;
    }
}

// K3: combine. One block per batch b.
//  M = max_c m_c; L = sum_c l_c*exp(m_c-M);
//  ctx[b][d] = sum_c pctx[c][b][d]*exp(m_c-M) / L;
//  attn[b][s] = exp(pscores[b][s]-M)/L   (exact softmax).
__global__ void __launch_bounds__(256) combine_kernel(
    const float* __restrict__ pscores, const float* __restrict__ pctx,
    const float* __restrict__ ml, float* __restrict__ ctx,
    float* __restrict__ attn) {
    const int b = blockIdx.x;
    const int t = threadIdx.x;
    __shared__ float eF[64];
    __shared__ float bc[2];
    if (t < 64) {
        float m = ml[(b * 64 + t) * 2];
        float l = ml[(b * 64 + t) * 2 + 1];
        float M = m;
        for (int o = 32; o; o >>= 1) M = fmaxf(M, __shfl_xor(M, o));
        float e  = __expf(m - M);
        float Lp = l * e;
        for (int o = 32; o; o >>= 1) Lp += __shfl_xor(Lp, o);
        eF[t] = e;
        if (t == 0) { bc[0] = M; bc[1] = 1.0f / Lp; }
    }
    __syncthreads();
    const float M = bc[0], invL = bc[1];
    // ctx: thread owns d-pair
    {
        const int d0 = t * 2;
        float cx = 0.f, cy = 0.f;
#pragma unroll 8
        for (int c = 0; c < 64; c++) {
            floatx2 v = *(const floatx2*)&pctx[((size_t)c * NB + b) * ND + d0];
            float e = eF[c];
            cx += e * v.x;
            cy += e * v.y;
        }
        ctx[b * ND + d0]     = cx * invL;
        ctx[b * ND + d0 + 1] = cy * invL;
    }
    // attn
    const float* srow = pscores + (size_t)b * NS;
    float* ao = attn + (size_t)b * NS;
#pragma unroll
    for (int i = 0; i < 16; i++)
        ao[t + i * 256] = __expf(srow[t + i * 256] - M) * invL;
}

extern "C" void kernel_launch(void* const* d_in, const int* in_sizes, int n_in,
                              void* d_out, int out_size, void* d_ws, size_t ws_size,
                              hipStream_t stream) {
    const float* query  = (const float*)d_in[0];
    const float* values = (const float*)d_in[1];
    const float* W1     = (const float*)d_in[2];
    const float* b1     = (const float*)d_in[3];
    const float* W2     = (const float*)d_in[4];
    const float* b2     = (const float*)d_in[5];
    const float* V      = (const float*)d_in[6];
    // d_in[7] = bv: uniform shift over softmax axis -> no effect on outputs. Dropped.

    float* ctx_out  = (float*)d_out;               // [32,512]
    float* attn_out = (float*)d_out + NB * ND;     // [32,4096]

    char* ws = (char*)d_ws;
    float*          qb      = (float*)ws;                              // 64 KB
    unsigned short* W2Tt    = (unsigned short*)(ws + (64 << 10));      // 512 KB
    float*          pscores = (float*)(ws + (576 << 10));              // 512 KB: [32][4096]
    float*          pctx    = (float*)(ws + (1088 << 10));             // 4 MB: [64][32][512]
    float*          ml      = (float*)(ws + (5184 << 10));             // 16 KB: [32][64][2]

    prep_kernel<<<384, 256, 0, stream>>>(query, W1, b1, b2, W2, qb, W2Tt);
    scores_ctx_kernel<<<dim3(64, 32), 256, 0, stream>>>(values, W2Tt, qb, V, pscores, pctx, ml);
    combine_kernel<<<NB, 256, 0, stream>>>(pscores, pctx, ml, ctx_out, attn_out);
}